// Round 1
// baseline (133.021 us; speedup 1.0000x reference)
//
#include <hip/hip_runtime.h>

// DenSparse: out[b, dst_e] += w_e * x[b, src_e]
// B=32, IN=OUT=65536, NNZ=1048576
// Strategy: transpose x -> x_t[IN][32], scatter-accumulate into out_t[OUT][32]
// (batch-innermost so each edge's 32 batch lanes hit one 128B line for both
// the gather and the atomic scatter), then transpose out_t -> out[32][OUT].

#define IN_SIZE  65536
#define OUT_SIZE 65536
#define BATCH    32

// ---------------- zero workspace accumulator ----------------
__global__ void zero_f4(float4* __restrict__ p, int n4) {
    int i = blockIdx.x * blockDim.x + threadIdx.x;
    if (i < n4) p[i] = make_float4(0.f, 0.f, 0.f, 0.f);
}

// ---------------- x[32][IN] -> x_t[IN][32] ----------------
// 1024 threads, one 32x32 tile per block. Reads coalesced along IN,
// writes coalesced along x_t's flat layout. 33-pad kills bank conflicts.
__global__ void transpose_in(const float* __restrict__ x, float* __restrict__ xt) {
    __shared__ float tile[32][33];
    int i0 = blockIdx.x * 32;
    int tx = threadIdx.x & 31;   // fast index
    int ty = threadIdx.x >> 5;   // slow index
    // tile[b][iofs] = x[b][i0+iofs]
    tile[ty][tx] = x[(size_t)ty * IN_SIZE + i0 + tx];
    __syncthreads();
    // xt[(i0+ty)*32 + tx] = x[tx][i0+ty]
    xt[((size_t)(i0 + ty)) * BATCH + tx] = tile[tx][ty];
}

// ---------------- out_t[OUT][32] -> out[32][OUT] ----------------
__global__ void transpose_out(const float* __restrict__ ot, float* __restrict__ out) {
    __shared__ float tile[32][33];
    int o0 = blockIdx.x * 32;
    int tx = threadIdx.x & 31;
    int ty = threadIdx.x >> 5;
    // tile[r][c] = out_t[o0+r][c]  (lanes tx coalesced along batch dim)
    tile[ty][tx] = ot[((size_t)(o0 + ty)) * BATCH + tx];
    __syncthreads();
    // out[ty][o0+tx] = out_t[o0+tx][ty]
    out[(size_t)ty * OUT_SIZE + o0 + tx] = tile[tx][ty];
}

// ---------------- main scatter: half-wave (32 lanes) per edge ----------------
__global__ void scatter_edges(const float* __restrict__ xt,
                              const float* __restrict__ w,
                              const int*   __restrict__ dst,
                              const int*   __restrict__ src,
                              float*       __restrict__ out_t,
                              int nnz) {
    int t = blockIdx.x * blockDim.x + threadIdx.x;
    int e = t >> 5;        // edge index
    int b = t & 31;        // batch lane
    if (e < nnz) {
        int   s  = src[e];   // same addr across 32 lanes -> broadcast
        int   d  = dst[e];
        float wv = w[e];
        float v = wv * xt[(size_t)s * BATCH + b];       // one 128B line / edge
        atomicAdd(&out_t[(size_t)d * BATCH + b], v);    // one 128B line / edge
    }
}

// ---------------- fallback: direct layout (if ws too small) ----------------
__global__ void scatter_direct(const float* __restrict__ x,
                               const float* __restrict__ w,
                               const int*   __restrict__ dst,
                               const int*   __restrict__ src,
                               float*       __restrict__ out,
                               int nnz) {
    int t = blockIdx.x * blockDim.x + threadIdx.x;
    int e = t >> 5;
    int b = t & 31;
    if (e < nnz) {
        int   s  = src[e];
        int   d  = dst[e];
        float wv = w[e];
        atomicAdd(&out[(size_t)b * OUT_SIZE + d], wv * x[(size_t)b * IN_SIZE + s]);
    }
}

extern "C" void kernel_launch(void* const* d_in, const int* in_sizes, int n_in,
                              void* d_out, int out_size, void* d_ws, size_t ws_size,
                              hipStream_t stream) {
    const float* x   = (const float*)d_in[0];   // [32][65536]
    const float* w   = (const float*)d_in[1];   // [NNZ]
    const int*   dst = (const int*)d_in[2];     // [NNZ]
    const int*   src = (const int*)d_in[3];     // [NNZ]
    float*       out = (float*)d_out;           // [32][65536]
    const int nnz = in_sizes[1];

    const size_t xt_bytes  = (size_t)IN_SIZE * BATCH * sizeof(float);   // 8 MB
    const size_t ot_bytes  = (size_t)OUT_SIZE * BATCH * sizeof(float);  // 8 MB

    if (ws_size >= xt_bytes + ot_bytes) {
        float* xt = (float*)d_ws;
        float* ot = (float*)((char*)d_ws + xt_bytes);

        // zero the accumulator (must happen every call — no cross-call state)
        {
            int n4 = OUT_SIZE * BATCH / 4;
            zero_f4<<<(n4 + 255) / 256, 256, 0, stream>>>((float4*)ot, n4);
        }
        // x -> x_t
        transpose_in<<<IN_SIZE / 32, 1024, 0, stream>>>(x, xt);
        // scatter
        {
            long long total = (long long)nnz * 32;
            int blocks = (int)((total + 255) / 256);
            scatter_edges<<<blocks, 256, 0, stream>>>(xt, w, dst, src, ot, nnz);
        }
        // out_t -> out
        transpose_out<<<OUT_SIZE / 32, 1024, 0, stream>>>(ot, out);
    } else {
        // fallback: zero d_out, atomics in native layout
        int n4 = out_size / 4;
        zero_f4<<<(n4 + 255) / 256, 256, 0, stream>>>((float4*)d_out, n4);
        long long total = (long long)nnz * 32;
        int blocks = (int)((total + 255) / 256);
        scatter_direct<<<blocks, 256, 0, stream>>>(x, w, dst, src, out, nnz);
    }
}